// Round 1
// baseline (1385.601 us; speedup 1.0000x reference)
//
#include <hip/hip_runtime.h>
#include <stdint.h>

#define TOKENS 4096          // B*S
#define HDIM   4096
#define IDIM   11008
#define WELEMS 45088768L     // 11008*4096 (all three weights same element count)

using i32x4 = __attribute__((ext_vector_type(4))) int;
using s8x16 = __attribute__((ext_vector_type(16))) signed char;

__device__ __forceinline__ void async_load16(const void* g, void* l) {
  __builtin_amdgcn_global_load_lds(
      (const __attribute__((address_space(1))) void*)g,
      (__attribute__((address_space(3))) void*)l, 16, 0, 0);
}

// ---------------- weight |.| sum (fp64, deterministic-enough) ----------------
__global__ __launch_bounds__(256) void wsum_kernel(
    const float* __restrict__ w0, const float* __restrict__ w1,
    const float* __restrict__ w2, double* __restrict__ dsum) {
  const float* w = (blockIdx.y == 0) ? w0 : (blockIdx.y == 1) ? w1 : w2;
  const long n4 = WELEMS / 4;
  long i = (long)blockIdx.x * blockDim.x + threadIdx.x;
  const long stride = (long)gridDim.x * blockDim.x;
  double s = 0.0;
  for (; i < n4; i += stride) {
    float4 v = ((const float4*)w)[i];
    s += (double)fabsf(v.x); s += (double)fabsf(v.y);
    s += (double)fabsf(v.z); s += (double)fabsf(v.w);
  }
  __shared__ double red[256];
  red[threadIdx.x] = s;
  __syncthreads();
  for (int off = 128; off; off >>= 1) {
    if (threadIdx.x < (unsigned)off) red[threadIdx.x] += red[threadIdx.x + off];
    __syncthreads();
  }
  if (threadIdx.x == 0) atomicAdd(&dsum[blockIdx.y], red[0]);
}

__global__ void wscale_kernel(const double* __restrict__ dsum, double* __restrict__ wsc) {
  int i = threadIdx.x;
  if (i < 3) {
    double mean = dsum[i] / (double)WELEMS;
    wsc[i] = 1.0 / fmax(mean, 1e-5);
  }
}

// ---------------- weight ternary quant ----------------
__global__ __launch_bounds__(256) void wquant_kernel(
    const float* __restrict__ w0, const float* __restrict__ w1, const float* __restrict__ w2,
    int8_t* __restrict__ q0, int8_t* __restrict__ q1, int8_t* __restrict__ q2,
    const double* __restrict__ wsc) {
  const int wi = blockIdx.y;
  const float* w = (wi == 0) ? w0 : (wi == 1) ? w1 : w2;
  int8_t* q = (wi == 0) ? q0 : (wi == 1) ? q1 : q2;
  const double sc = wsc[wi];
  long c = (long)blockIdx.x * blockDim.x + threadIdx.x;   // 16-element chunk
  if (c * 16 >= WELEMS) return;
  const float4* src = (const float4*)(w + c * 16);
  s8x16 outv;
  #pragma unroll
  for (int j = 0; j < 4; ++j) {
    float4 v = src[j];
    double t0 = rint((double)v.x * sc); t0 = fmin(fmax(t0, -1.0), 1.0);
    double t1 = rint((double)v.y * sc); t1 = fmin(fmax(t1, -1.0), 1.0);
    double t2 = rint((double)v.z * sc); t2 = fmin(fmax(t2, -1.0), 1.0);
    double t3 = rint((double)v.w * sc); t3 = fmin(fmax(t3, -1.0), 1.0);
    outv[j*4+0] = (signed char)(int)t0; outv[j*4+1] = (signed char)(int)t1;
    outv[j*4+2] = (signed char)(int)t2; outv[j*4+3] = (signed char)(int)t3;
  }
  *(s8x16*)(q + c * 16) = outv;
}

// ---------------- per-token activation quant of x ----------------
__global__ __launch_bounds__(256) void xquant_kernel(
    const float* __restrict__ x, int8_t* __restrict__ xq, double* __restrict__ sx) {
  const int row = blockIdx.x;
  const float* xr = x + (long)row * HDIM;
  const float4* xr4 = (const float4*)xr;
  float m = 0.f;
  for (int i = threadIdx.x; i < HDIM / 4; i += 256) {
    float4 v = xr4[i];
    m = fmaxf(m, fmaxf(fmaxf(fabsf(v.x), fabsf(v.y)), fmaxf(fabsf(v.z), fabsf(v.w))));
  }
  __shared__ float red[256];
  red[threadIdx.x] = m;
  __syncthreads();
  for (int off = 128; off; off >>= 1) {
    if (threadIdx.x < (unsigned)off) red[threadIdx.x] = fmaxf(red[threadIdx.x], red[threadIdx.x + off]);
    __syncthreads();
  }
  __shared__ double s_sc;
  if (threadIdx.x == 0) {
    double sc = 127.0 / fmax((double)red[0], 1e-5);
    sx[row] = sc;
    s_sc = sc;
  }
  __syncthreads();
  const double sc = s_sc;
  // each thread quantizes its contiguous 16-element chunk
  s8x16 outv;
  #pragma unroll
  for (int j = 0; j < 4; ++j) {
    float4 v = xr4[threadIdx.x * 4 + j];
    double t0 = rint((double)v.x * sc); t0 = fmin(fmax(t0, -128.0), 127.0);
    double t1 = rint((double)v.y * sc); t1 = fmin(fmax(t1, -128.0), 127.0);
    double t2 = rint((double)v.z * sc); t2 = fmin(fmax(t2, -128.0), 127.0);
    double t3 = rint((double)v.w * sc); t3 = fmin(fmax(t3, -128.0), 127.0);
    outv[j*4+0] = (signed char)(int)t0; outv[j*4+1] = (signed char)(int)t1;
    outv[j*4+2] = (signed char)(int)t2; outv[j*4+3] = (signed char)(int)t3;
  }
  *(s8x16*)(xq + (long)row * HDIM + threadIdx.x * 16) = outv;
}

// ---------------- fused gate+up i8 GEMM -> h = relu(g)^2 * u, row absmax ----------------
__global__ __launch_bounds__(256, 2) void gemm1_kernel(
    const int8_t* __restrict__ Aq, const int8_t* __restrict__ Bg, const int8_t* __restrict__ Bu,
    const double* __restrict__ sx, const double* __restrict__ wsc,
    float* __restrict__ H, unsigned int* __restrict__ hmax) {
  __shared__ __align__(16) int8_t As[128 * 64];
  __shared__ __align__(16) int8_t Bsg[128 * 64];
  __shared__ __align__(16) int8_t Bsu[128 * 64];
  __shared__ unsigned int smax[128];

  const int tid = threadIdx.x;
  const int l = tid & 63;
  const int wv = tid >> 6;
  const int wm = (wv >> 1) * 64;
  const int wn = (wv & 1) * 64;
  const int row0 = blockIdx.y * 128;
  const int col0 = blockIdx.x * 128;

  i32x4 accg[4][4], accu[4][4];
  #pragma unroll
  for (int i = 0; i < 4; i++)
    #pragma unroll
    for (int j = 0; j < 4; j++) { accg[i][j] = i32x4{0,0,0,0}; accu[i][j] = i32x4{0,0,0,0}; }

  const int off0 = tid * 16;
  const int rs = off0 >> 6;      // row within tile for stage s=0
  const int cs = off0 & 63;

  for (int k0 = 0; k0 < HDIM; k0 += 64) {
    #pragma unroll
    for (int s = 0; s < 2; ++s) {
      const int off = off0 + s * 4096;
      const int r = rs + s * 64;
      const long ga = (long)(row0 + r) * HDIM + k0 + cs;
      const long gb = (long)(col0 + r) * HDIM + k0 + cs;
      async_load16(Aq + ga, As + off);
      async_load16(Bg + gb, Bsg + off);
      async_load16(Bu + gb, Bsu + off);
    }
    __syncthreads();
    const int kq = (l >> 4) * 16;
    const int mr = l & 15;
    i32x4 af[4], bgf[4], buf_[4];
    #pragma unroll
    for (int t = 0; t < 4; t++) af[t] = *(const i32x4*)(As + (wm + t * 16 + mr) * 64 + kq);
    #pragma unroll
    for (int t = 0; t < 4; t++) {
      bgf[t] = *(const i32x4*)(Bsg + (wn + t * 16 + mr) * 64 + kq);
      buf_[t] = *(const i32x4*)(Bsu + (wn + t * 16 + mr) * 64 + kq);
    }
    #pragma unroll
    for (int mt = 0; mt < 4; mt++)
      #pragma unroll
      for (int nt = 0; nt < 4; nt++) {
        accg[mt][nt] = __builtin_amdgcn_mfma_i32_16x16x64_i8(af[mt], bgf[nt], accg[mt][nt], 0, 0, 0);
        accu[mt][nt] = __builtin_amdgcn_mfma_i32_16x16x64_i8(af[mt], buf_[nt], accu[mt][nt], 0, 0, 0);
      }
    __syncthreads();
  }

  if (tid < 128) smax[tid] = 0u;
  __syncthreads();
  const double swg = wsc[0], swu = wsc[1];
  #pragma unroll
  for (int mt = 0; mt < 4; mt++) {
    #pragma unroll
    for (int r = 0; r < 4; r++) {
      const int grow = wm + mt * 16 + (l >> 4) * 4 + r;          // local row 0..127
      const long growg = row0 + grow;
      const double sxr = sx[growg];
      const double dg = 1.0 / (sxr * swg);
      const double du = 1.0 / (sxr * swu);
      float am = 0.f;
      #pragma unroll
      for (int nt = 0; nt < 4; nt++) {
        const float g = (float)((double)accg[mt][nt][r] * dg);
        const float u = (float)((double)accu[mt][nt][r] * du);
        const float gr = g > 0.f ? g * g : 0.f;
        const float h = gr * u;
        H[growg * IDIM + col0 + wn + nt * 16 + (l & 15)] = h;
        am = fmaxf(am, fabsf(h));
      }
      atomicMax(&smax[grow], __float_as_uint(am));
    }
  }
  __syncthreads();
  if (tid < 128) atomicMax(&hmax[row0 + tid], smax[tid]);
}

// ---------------- quantize h per token ----------------
__global__ __launch_bounds__(256) void hquant_kernel(
    const float* __restrict__ H, int8_t* __restrict__ hq, const unsigned int* __restrict__ hmax) {
  const long c = (long)blockIdx.x * blockDim.x + threadIdx.x;   // 16-elem chunk; IDIM%16==0
  const long nchunks = (long)TOKENS * IDIM / 16;
  if (c >= nchunks) return;
  const int row = (int)(c / (IDIM / 16));
  const double sc = 127.0 / fmax((double)__uint_as_float(hmax[row]), 1e-5);
  const float4* src = (const float4*)(H + c * 16);
  s8x16 outv;
  #pragma unroll
  for (int j = 0; j < 4; ++j) {
    float4 v = src[j];
    double t0 = rint((double)v.x * sc); t0 = fmin(fmax(t0, -128.0), 127.0);
    double t1 = rint((double)v.y * sc); t1 = fmin(fmax(t1, -128.0), 127.0);
    double t2 = rint((double)v.z * sc); t2 = fmin(fmax(t2, -128.0), 127.0);
    double t3 = rint((double)v.w * sc); t3 = fmin(fmax(t3, -128.0), 127.0);
    outv[j*4+0] = (signed char)(int)t0; outv[j*4+1] = (signed char)(int)t1;
    outv[j*4+2] = (signed char)(int)t2; outv[j*4+3] = (signed char)(int)t3;
  }
  *(s8x16*)(hq + c * 16) = outv;
}

// ---------------- down-proj i8 GEMM -> out fp32 ----------------
__global__ __launch_bounds__(256, 2) void gemm2_kernel(
    const int8_t* __restrict__ Aq, const int8_t* __restrict__ Bq,
    const unsigned int* __restrict__ hmax, const double* __restrict__ wsc,
    float* __restrict__ out) {
  __shared__ __align__(16) int8_t As[128 * 64];
  __shared__ __align__(16) int8_t Bs[128 * 64];

  const int tid = threadIdx.x;
  const int l = tid & 63;
  const int wv = tid >> 6;
  const int wm = (wv >> 1) * 64;
  const int wn = (wv & 1) * 64;
  const int row0 = blockIdx.y * 128;
  const int col0 = blockIdx.x * 128;

  i32x4 acc[4][4];
  #pragma unroll
  for (int i = 0; i < 4; i++)
    #pragma unroll
    for (int j = 0; j < 4; j++) acc[i][j] = i32x4{0,0,0,0};

  const int off0 = tid * 16;
  const int rs = off0 >> 6;
  const int cs = off0 & 63;

  for (int k0 = 0; k0 < IDIM; k0 += 64) {
    #pragma unroll
    for (int s = 0; s < 2; ++s) {
      const int off = off0 + s * 4096;
      const int r = rs + s * 64;
      const long ga = (long)(row0 + r) * IDIM + k0 + cs;
      const long gb = (long)(col0 + r) * IDIM + k0 + cs;
      async_load16(Aq + ga, As + off);
      async_load16(Bq + gb, Bs + off);
    }
    __syncthreads();
    const int kq = (l >> 4) * 16;
    const int mr = l & 15;
    i32x4 af[4], bf[4];
    #pragma unroll
    for (int t = 0; t < 4; t++) af[t] = *(const i32x4*)(As + (wm + t * 16 + mr) * 64 + kq);
    #pragma unroll
    for (int t = 0; t < 4; t++) bf[t] = *(const i32x4*)(Bs + (wn + t * 16 + mr) * 64 + kq);
    #pragma unroll
    for (int mt = 0; mt < 4; mt++)
      #pragma unroll
      for (int nt = 0; nt < 4; nt++)
        acc[mt][nt] = __builtin_amdgcn_mfma_i32_16x16x64_i8(af[mt], bf[nt], acc[mt][nt], 0, 0, 0);
    __syncthreads();
  }

  const double swd = wsc[2];
  #pragma unroll
  for (int mt = 0; mt < 4; mt++) {
    #pragma unroll
    for (int r = 0; r < 4; r++) {
      const int grow = wm + mt * 16 + (l >> 4) * 4 + r;
      const long growg = row0 + grow;
      const double shr = 127.0 / fmax((double)__uint_as_float(hmax[growg]), 1e-5);
      const double inv = 1.0 / (shr * swd);
      #pragma unroll
      for (int nt = 0; nt < 4; nt++)
        out[growg * HDIM + col0 + wn + nt * 16 + (l & 15)] = (float)((double)acc[mt][nt][r] * inv);
    }
  }
}

extern "C" void kernel_launch(void* const* d_in, const int* in_sizes, int n_in,
                              void* d_out, int out_size, void* d_ws, size_t ws_size,
                              hipStream_t stream) {
  const float* x  = (const float*)d_in[0];
  const float* wg = (const float*)d_in[1];
  const float* wu = (const float*)d_in[2];
  const float* wd = (const float*)d_in[3];
  float* out = (float*)d_out;

  char* ws = (char*)d_ws;
  // workspace layout
  double*   dsum  = (double*)ws;                       // [4]   @0
  double*   wsc   = (double*)(ws + 32);                // [3]   @32
  double*   sx    = (double*)(ws + 64);                // [4096]@64
  unsigned* hmaxb = (unsigned*)(ws + 64 + TOKENS * 8); // [4096]@32832
  int8_t*   xq    = (int8_t*)(ws + 131072);
  int8_t*   wqg   = xq + (long)TOKENS * HDIM;          // +16,777,216
  int8_t*   wqu   = wqg + WELEMS;
  int8_t*   wqd   = wqu + WELEMS;
  int8_t*   hq    = wqd + WELEMS;
  float*    H     = (float*)(hq + WELEMS);             // 180,355,072 B
  const size_t needed = 131072 + (size_t)TOKENS * HDIM + 4 * (size_t)WELEMS
                      + (size_t)TOKENS * IDIM * sizeof(float);
  if (ws_size < needed) {               // distinctive failure: zeroed output
    hipMemsetAsync(d_out, 0, (size_t)out_size * sizeof(float), stream);
    return;
  }

  hipMemsetAsync(ws, 0, 65536, stream);  // zeros dsum + sx + hmax region

  { dim3 g(1024, 3); wsum_kernel<<<g, 256, 0, stream>>>(wg, wu, wd, dsum); }
  wscale_kernel<<<1, 64, 0, stream>>>(dsum, wsc);
  { dim3 g((unsigned)(WELEMS / (256 * 16)), 3);  // 11008 x 3
    wquant_kernel<<<g, 256, 0, stream>>>(wg, wu, wd, wqg, wqu, wqd, wsc); }
  xquant_kernel<<<TOKENS, 256, 0, stream>>>(x, xq, sx);
  { dim3 g(IDIM / 128, TOKENS / 128);   // 86 x 32
    gemm1_kernel<<<g, 256, 0, stream>>>(xq, wqg, wqu, sx, wsc, H, hmaxb); }
  hquant_kernel<<<(unsigned)((long)TOKENS * IDIM / 16 / 256), 256, 0, stream>>>(H, hq, hmaxb);
  { dim3 g(HDIM / 128, TOKENS / 128);   // 32 x 32
    gemm2_kernel<<<g, 256, 0, stream>>>(hq, wqd, hmaxb, wsc, out); }
}